// Round 1
// baseline (1089.688 us; speedup 1.0000x reference)
//
#include <hip/hip_runtime.h>

typedef unsigned short ushort_t;
typedef __attribute__((ext_vector_type(8))) short short8;
typedef __attribute__((ext_vector_type(4))) float floatx4;

#define GAS __attribute__((address_space(1)))
#define LAS __attribute__((address_space(3)))

// ---------- bf16 helpers ----------
__device__ __forceinline__ float bf2f(ushort_t h) {
  union { unsigned int u; float f; } v; v.u = ((unsigned int)h) << 16; return v.f;
}
__device__ __forceinline__ ushort_t f2bf(float f) {  // round-to-nearest-even
  union { float f; unsigned int u; } v; v.f = f;
  unsigned int u = v.u;
  unsigned int r = (u + 0x7fffu + ((u >> 16) & 1u)) >> 16;
  return (ushort_t)r;
}
__device__ __forceinline__ float blo(unsigned int u) { union { unsigned int u; float f; } v; v.u = u << 16; return v.f; }
__device__ __forceinline__ float bhi(unsigned int u) { union { unsigned int u; float f; } v; v.u = u & 0xffff0000u; return v.f; }

// ---------- problem constants ----------
#define T_TOK 4096
#define DIM   1024
#define FDIM  4096
#define NEXP  8
#define MAXROWS 9216   // 8192 pairs + per-expert pad to 128

// ================= input dtype probe: 0 = bf16, 1 = fp32 =================
__global__ void detect_kernel(const ushort_t* __restrict__ xraw, int* __restrict__ dflag) {
  __shared__ int cnt;
  if (threadIdx.x == 0) cnt = 0;
  __syncthreads();
  int c = 0;
#pragma unroll
  for (int i = 0; i < 4; ++i) {
    ushort_t u = xraw[(threadIdx.x * 4 + i) * 2];   // even indices (fp32 low-mantissa halves)
    int e = (u >> 7) & 0xFF;
    if (e >= 100 && e <= 140) c++;
  }
  atomicAdd(&cnt, c);
  __syncthreads();
  if (threadIdx.x == 0) dflag[0] = (cnt > 600) ? 0 : 1;
}

// ================= cast/copy x -> bf16 xb =================
__global__ void __launch_bounds__(256) castx_kernel(const void* __restrict__ xraw,
                                                    const int* __restrict__ dflag,
                                                    ushort_t* __restrict__ xb) {
  const int t = blockIdx.x * 256 + threadIdx.x;     // 8 elements per thread
  const size_t base = (size_t)t * 8;
  if (dflag[0]) {
    const float4* f = (const float4*)((const float*)xraw + base);
    float4 a = f[0], b = f[1];
    ushort_t o[8] = { f2bf(a.x), f2bf(a.y), f2bf(a.z), f2bf(a.w),
                      f2bf(b.x), f2bf(b.y), f2bf(b.z), f2bf(b.w) };
    *(uint4*)(xb + base) = *(const uint4*)o;
  } else {
    *(uint4*)(xb + base) = *((const uint4*)xraw + t);
  }
}

// ================= router: 1 wave per token, fp64 logit accumulation =================
// Routing is a DISCRETE decision (top-2 selection): logits must be computed at
// full precision from the raw fp32 inputs or rare near-ties flip vs reference
// (round-3 absmax 0.67 signature: ~12 flipped tokens from bf16-quantized x).
__global__ void __launch_bounds__(256) router_kernel(
    const void* __restrict__ x_, const ushort_t* __restrict__ xb,
    const void* __restrict__ rw_, const void* __restrict__ rb_,
    const int* __restrict__ dflag,
    int* __restrict__ topk_idx, float* __restrict__ topk_wgt, int* __restrict__ counts) {
  const int lane = threadIdx.x & 63;
  const int w = threadIdx.x >> 6;
  const int t = blockIdx.x * 4 + w;
  const int isf32 = dflag[0];
  double logits[NEXP];
  if (isf32) {
    const float* xr = (const float*)x_ + (size_t)t * DIM;
    float xv[16];
#pragma unroll
    for (int i = 0; i < 8; ++i) {
      const float2 v = *(const float2*)(xr + i * 128 + lane * 2);
      xv[2*i] = v.x; xv[2*i+1] = v.y;
    }
#pragma unroll
    for (int e = 0; e < NEXP; ++e) {
      const float* wr = (const float*)rw_ + (size_t)e * DIM;
      double acc = 0.0;
#pragma unroll
      for (int i = 0; i < 8; ++i) {
        const float2 v = *(const float2*)(wr + i * 128 + lane * 2);
        acc += (double)xv[2*i] * (double)v.x + (double)xv[2*i+1] * (double)v.y;
      }
#pragma unroll
      for (int off = 32; off > 0; off >>= 1) acc += __shfl_xor(acc, off, 64);
      logits[e] = acc + (double)((const float*)rb_)[e];
    }
  } else {
    const ushort_t* xr = xb + (size_t)t * DIM;
    float xv[16];
#pragma unroll
    for (int i = 0; i < 8; ++i) {
      unsigned int u = *(const unsigned int*)(xr + i * 128 + lane * 2);
      xv[2*i] = blo(u); xv[2*i+1] = bhi(u);
    }
#pragma unroll
    for (int e = 0; e < NEXP; ++e) {
      const ushort_t* wr = (const ushort_t*)rw_ + (size_t)e * DIM;
      float acc = 0.f;
#pragma unroll
      for (int i = 0; i < 8; ++i) {
        unsigned int u = *(const unsigned int*)(wr + i * 128 + lane * 2);
        acc += xv[2*i] * blo(u) + xv[2*i+1] * bhi(u);
      }
#pragma unroll
      for (int off = 32; off > 0; off >>= 1) acc += __shfl_xor(acc, off, 64);
      logits[e] = (double)(acc + bf2f(((const ushort_t*)rb_)[e]));
    }
  }
  if (lane == 0) {
    double l1 = -1e300, l2 = -1e300; int i1 = 0, i2 = 0;
#pragma unroll
    for (int e = 0; e < NEXP; ++e) {
      double l = logits[e];
      if (l > l1) { l2 = l1; i2 = i1; l1 = l; i1 = e; }
      else if (l > l2) { l2 = l; i2 = e; }
    }
    float wa = (float)(1.0 / (1.0 + exp(l2 - l1)));   // softmax->top2->renorm
    topk_idx[2*t] = i1; topk_idx[2*t+1] = i2;
    topk_wgt[2*t] = wa; topk_wgt[2*t+1] = 1.f - wa;
    atomicAdd(&counts[i1], 1);
    atomicAdd(&counts[i2], 1);
  }
}

// ================= tiny scan: padded exclusive offsets =================
__global__ void scan_kernel(const int* __restrict__ counts, int* __restrict__ offsets) {
  if (threadIdx.x == 0 && blockIdx.x == 0) {
    int s = 0; offsets[0] = 0;
    for (int e = 0; e < NEXP; ++e) { s += (counts[e] + 127) & ~127; offsets[e + 1] = s; }
  }
}

// ================= scatter pairs into per-expert row lists =================
__global__ void __launch_bounds__(256) scatter_kernel(
    const int* __restrict__ topk_idx, const float* __restrict__ topk_wgt,
    const int* __restrict__ offsets, int* __restrict__ cursors,
    int* __restrict__ row_tok, float* __restrict__ row_wgt) {
  int p = blockIdx.x * 256 + threadIdx.x;   // 0..8191
  int e = topk_idx[p];
  int pos = atomicAdd(&cursors[e], 1);
  int r = offsets[e] + pos;
  row_tok[r] = p >> 1;
  row_wgt[r] = topk_wgt[p];
}

// ================= gather xb rows into packed Xg (bf16) =================
__global__ void __launch_bounds__(256) gather_kernel(
    const uint4* __restrict__ xb, const int* __restrict__ row_tok, uint4* __restrict__ Xg) {
  int tid = blockIdx.x * 256 + threadIdx.x;
  int r = tid >> 7, c = tid & 127;
  int tok = row_tok[r];
  Xg[(size_t)r * 128 + c] = xb[(size_t)tok * 128 + c];
}

// ================= transpose: src [R][C] (fp32 or bf16) -> dst bf16 [C][R] =================
__global__ void __launch_bounds__(256) transpose_kernel(
    const void* __restrict__ src_, ushort_t* __restrict__ dst, int R, int C,
    const int* __restrict__ dflag) {
  __shared__ unsigned int tile[64][33];
  const int e = blockIdx.z;
  const int r0 = blockIdx.y * 64;
  const int c0 = blockIdx.x * 64;
  const int tx = threadIdx.x;
  if (dflag[0]) {
    const float* S = (const float*)src_ + (size_t)e * R * C;
#pragma unroll
    for (int it = 0; it < 8; ++it) {
      int slot = tx + it * 256;       // 2048 slots: 64 rows x 32 uint-cols
      int r = slot >> 5;
      int c2 = slot & 31;
      const float2 v = *(const float2*)(S + (size_t)(r0 + r) * C + c0 + c2 * 2);
      tile[r][c2] = (unsigned int)f2bf(v.x) | ((unsigned int)f2bf(v.y) << 16);
    }
  } else {
    const ushort_t* S = (const ushort_t*)src_ + (size_t)e * R * C;
#pragma unroll
    for (int it = 0; it < 2; ++it) {
      int slot = tx + it * 256;       // 512 slots: 64 rows x 8 chunks
      int r = slot >> 3;
      int cc = slot & 7;
      const uint4 v = *(const uint4*)(S + (size_t)(r0 + r) * C + c0 + cc * 8);
      tile[r][cc*4+0] = v.x; tile[r][cc*4+1] = v.y; tile[r][cc*4+2] = v.z; tile[r][cc*4+3] = v.w;
    }
  }
  __syncthreads();
#pragma unroll
  for (int it = 0; it < 2; ++it) {
    int slot = tx + it * 256;
    int c = slot >> 3;
    int rr = (slot & 7) * 8;
    unsigned int o[4];
#pragma unroll
    for (int q = 0; q < 4; ++q) {
      unsigned int a = tile[rr + 2*q][c >> 1];
      unsigned int b = tile[rr + 2*q + 1][c >> 1];
      unsigned int ha = (c & 1) ? (a >> 16) : (a & 0xffffu);
      unsigned int hb = (c & 1) ? (b >> 16) : (b & 0xffffu);
      o[q] = ha | (hb << 16);
    }
    *(uint4*)(dst + (size_t)e * R * C + (size_t)(c0 + c) * R + r0 + rr) = *(const uint4*)o;
  }
}

// ================= GEMM helpers (m97 structure + bank swizzle) =================
__device__ __forceinline__ int swz(int r) { return (r >> 1) & 3; }

__device__ __forceinline__ void stage_tile(const ushort_t* gbase, int gstride,
                                           int row0, int k0, short* lds_tile,
                                           int wid, int lane) {
#pragma unroll
  for (int tloop = 0; tloop < 2; ++tloop) {
    int tr0 = wid * 32 + tloop * 16;
    int r = tr0 + (lane >> 2);
    int g = (lane & 3) ^ swz(r);
    const ushort_t* gp = gbase + (size_t)(row0 + r) * gstride + k0 + g * 8;
    __builtin_amdgcn_global_load_lds((const GAS void*)gp,
                                     (LAS void*)(lds_tile + tr0 * 32), 16, 0, 0);
  }
}

__device__ __forceinline__ short8 frag_ld(const short* tile, int row, int q) {
  return *(const short8*)(tile + row * 32 + ((q ^ swz(row)) << 3));
}

// ================= GEMM1: H = silu(Xg@W1t^T) * (Xg@W3t^T) =================
__global__ void __launch_bounds__(256) gemm1_kernel(
    const ushort_t* __restrict__ Xg, const ushort_t* __restrict__ w1t, const ushort_t* __restrict__ w3t,
    const int* __restrict__ offsets, ushort_t* __restrict__ H) {
  const int e = blockIdx.z;
  const int off_e = offsets[e];
  const int nrows = offsets[e + 1] - off_e;
  if ((int)blockIdx.y * 128 >= nrows) return;
  const int row0 = off_e + blockIdx.y * 128;
  const int fbase = blockIdx.x * 128;
  const ushort_t* w1e = w1t + (size_t)e * FDIM * DIM;
  const ushort_t* w3e = w3t + (size_t)e * FDIM * DIM;

  __shared__ __align__(16) short As[4096];
  __shared__ __align__(16) short B1s[4096];
  __shared__ __align__(16) short B3s[4096];

  const int lane = threadIdx.x & 63;
  const int wid = threadIdx.x >> 6;
  const int wrow = (wid >> 1) * 64;
  const int wcol = (wid & 1) * 64;
  const int l15 = lane & 15;
  const int quad = lane >> 4;

  floatx4 acc1[4][4], acc3[4][4];
  const floatx4 z4 = {0.f, 0.f, 0.f, 0.f};
#pragma unroll
  for (int i = 0; i < 4; ++i)
#pragma unroll
    for (int j = 0; j < 4; ++j) { acc1[i][j] = z4; acc3[i][j] = z4; }

  for (int k0 = 0; k0 < DIM; k0 += 32) {
    __syncthreads();
    stage_tile(Xg,  DIM, row0,  k0, As,  wid, lane);
    stage_tile(w1e, DIM, fbase, k0, B1s, wid, lane);
    stage_tile(w3e, DIM, fbase, k0, B3s, wid, lane);
    __syncthreads();
    short8 a[4], b1[4], b3[4];
#pragma unroll
    for (int i = 0; i < 4; ++i) a[i] = frag_ld(As, wrow + i * 16 + l15, quad);
#pragma unroll
    for (int j = 0; j < 4; ++j) {
      b1[j] = frag_ld(B1s, wcol + j * 16 + l15, quad);
      b3[j] = frag_ld(B3s, wcol + j * 16 + l15, quad);
    }
#pragma unroll
    for (int i = 0; i < 4; ++i)
#pragma unroll
      for (int j = 0; j < 4; ++j) {
        acc1[i][j] = __builtin_amdgcn_mfma_f32_16x16x32_bf16(a[i], b1[j], acc1[i][j], 0, 0, 0);
        acc3[i][j] = __builtin_amdgcn_mfma_f32_16x16x32_bf16(a[i], b3[j], acc3[i][j], 0, 0, 0);
      }
  }

#pragma unroll
  for (int i = 0; i < 4; ++i)
#pragma unroll
    for (int j = 0; j < 4; ++j) {
      const int n = fbase + wcol + j * 16 + l15;
#pragma unroll
      for (int p = 0; p < 4; ++p) {
        const int rl = wrow + i * 16 + quad * 4 + p;
        float zt = acc1[i][j][p];
        float vt = acc3[i][j][p];
        float s = zt / (1.f + __expf(-zt));   // silu
        H[(size_t)(row0 + rl) * FDIM + n] = f2bf(s * vt);
      }
    }
}

// ================= GEMM2: out[tok] += wgt * (H @ W2t^T)  (fp32 output) =================
__global__ void __launch_bounds__(256) gemm2_kernel(
    const ushort_t* __restrict__ H, const ushort_t* __restrict__ w2t,
    const int* __restrict__ offsets, const int* __restrict__ row_tok,
    const float* __restrict__ row_wgt, float* __restrict__ out) {
  const int e = blockIdx.z;
  const int off_e = offsets[e];
  const int nrows = offsets[e + 1] - off_e;
  if ((int)blockIdx.y * 128 >= nrows) return;
  const int row0 = off_e + blockIdx.y * 128;
  const int dbase = blockIdx.x * 128;
  const ushort_t* w2e = w2t + (size_t)e * DIM * FDIM;

  __shared__ __align__(16) short As[4096];
  __shared__ __align__(16) short Bs[4096];

  const int lane = threadIdx.x & 63;
  const int wid = threadIdx.x >> 6;
  const int wrow = (wid >> 1) * 64;
  const int wcol = (wid & 1) * 64;
  const int l15 = lane & 15;
  const int quad = lane >> 4;

  floatx4 acc[4][4];
  const floatx4 z4 = {0.f, 0.f, 0.f, 0.f};
#pragma unroll
  for (int i = 0; i < 4; ++i)
#pragma unroll
    for (int j = 0; j < 4; ++j) acc[i][j] = z4;

  for (int k0 = 0; k0 < FDIM; k0 += 32) {
    __syncthreads();
    stage_tile(H,   FDIM, row0,  k0, As, wid, lane);
    stage_tile(w2e, FDIM, dbase, k0, Bs, wid, lane);
    __syncthreads();
    short8 a[4], b[4];
#pragma unroll
    for (int i = 0; i < 4; ++i) a[i] = frag_ld(As, wrow + i * 16 + l15, quad);
#pragma unroll
    for (int j = 0; j < 4; ++j) b[j] = frag_ld(Bs, wcol + j * 16 + l15, quad);
#pragma unroll
    for (int i = 0; i < 4; ++i)
#pragma unroll
      for (int j = 0; j < 4; ++j)
        acc[i][j] = __builtin_amdgcn_mfma_f32_16x16x32_bf16(a[i], b[j], acc[i][j], 0, 0, 0);
  }

#pragma unroll
  for (int i = 0; i < 4; ++i) {
    int tok[4]; float wgt[4];
#pragma unroll
    for (int p = 0; p < 4; ++p) {
      int rl = row0 + wrow + i * 16 + quad * 4 + p;
      tok[p] = row_tok[rl];
      wgt[p] = row_wgt[rl];   // 0.0 on padding rows
    }
#pragma unroll
    for (int j = 0; j < 4; ++j) {
      int n = dbase + wcol + j * 16 + l15;
#pragma unroll
      for (int p = 0; p < 4; ++p)
        atomicAdd(&out[(size_t)tok[p] * DIM + n], wgt[p] * acc[i][j][p]);
    }
  }
}

// ================= host launch =================
extern "C" void kernel_launch(void* const* d_in, const int* in_sizes, int n_in,
                              void* d_out, int out_size, void* d_ws, size_t ws_size,
                              hipStream_t stream) {
  const void* x  = d_in[0];
  const void* rw = d_in[1];
  const void* rb = d_in[2];
  const void* w1 = d_in[3];
  const void* w2 = d_in[4];
  const void* w3 = d_in[5];
  float* out = (float*)d_out;   // fp32 output

  char* ws = (char*)d_ws;
  size_t off = 0;
  auto alloc = [&](size_t bytes) { size_t o = off; off += (bytes + 255) & ~(size_t)255; return o; };
  int*      dflag    = (int*)(ws + alloc(64));
  int*      counts   = (int*)(ws + alloc(64));
  int*      cursors  = (int*)(ws + alloc(64));
  int*      offsets  = (int*)(ws + alloc(64));
  int*      topk_idx = (int*)(ws + alloc((size_t)T_TOK * 2 * 4));
  float*    topk_wgt = (float*)(ws + alloc((size_t)T_TOK * 2 * 4));
  int*      row_tok  = (int*)(ws + alloc((size_t)MAXROWS * 4));
  float*    row_wgt  = (float*)(ws + alloc((size_t)MAXROWS * 4));
  ushort_t* xb       = (ushort_t*)(ws + alloc((size_t)T_TOK * DIM * 2));
  ushort_t* Xg       = (ushort_t*)(ws + alloc((size_t)MAXROWS * DIM * 2));
  ushort_t* Hbuf     = (ushort_t*)(ws + alloc((size_t)MAXROWS * FDIM * 2));
  ushort_t* w1t      = (ushort_t*)(ws + alloc((size_t)NEXP * FDIM * DIM * 2));
  ushort_t* w3t      = (ushort_t*)(ws + alloc((size_t)NEXP * FDIM * DIM * 2));
  ushort_t* w2t      = (ushort_t*)(ws + alloc((size_t)NEXP * DIM * FDIM * 2));

  hipMemsetAsync(counts, 0, 64, stream);
  hipMemsetAsync(cursors, 0, 64, stream);
  hipMemsetAsync(row_tok, 0, (size_t)MAXROWS * 4, stream);
  hipMemsetAsync(row_wgt, 0, (size_t)MAXROWS * 4, stream);
  // Zero exactly the harness-provided output buffer (harness poisons d_out with
  // 0xAA; gemm2 accumulates with atomicAdd so it must start at 0). Using
  // out_size instead of a hard-coded byte count — if the harness sizes d_out
  // differently than fp32[4096][1024], a fixed-size memset would corrupt the
  // allocation past the buffer (host abort, no device fault message).
  hipMemsetAsync(out, 0, (size_t)out_size, stream);

  detect_kernel<<<1, 256, 0, stream>>>((const ushort_t*)x, dflag);
  castx_kernel<<<(T_TOK * DIM / 8) / 256, 256, 0, stream>>>(x, dflag, xb);
  router_kernel<<<T_TOK / 4, 256, 0, stream>>>(x, xb, rw, rb, dflag, topk_idx, topk_wgt, counts);
  scan_kernel<<<1, 64, 0, stream>>>(counts, offsets);
  scatter_kernel<<<(T_TOK * 2) / 256, 256, 0, stream>>>(topk_idx, topk_wgt, offsets, cursors, row_tok, row_wgt);
  gather_kernel<<<(MAXROWS * 128) / 256, 256, 0, stream>>>((const uint4*)xb, row_tok, (uint4*)Xg);
  // w1,w3: [D][F] -> [F][D];  w2: [F][D] -> [D][F]
  transpose_kernel<<<dim3(FDIM / 64, DIM / 64, NEXP), 256, 0, stream>>>(w1, w1t, DIM, FDIM, dflag);
  transpose_kernel<<<dim3(FDIM / 64, DIM / 64, NEXP), 256, 0, stream>>>(w3, w3t, DIM, FDIM, dflag);
  transpose_kernel<<<dim3(DIM / 64, FDIM / 64, NEXP), 256, 0, stream>>>(w2, w2t, FDIM, DIM, dflag);
  gemm1_kernel<<<dim3(FDIM / 128, 72, NEXP), 256, 0, stream>>>(Xg, w1t, w3t, offsets, Hbuf);
  gemm2_kernel<<<dim3(DIM / 128, 72, NEXP), 256, 0, stream>>>(Hbuf, w2t, offsets, row_tok, row_wgt, out);
}

// Round 2
// 988.936 us; speedup vs baseline: 1.1019x; 1.1019x over previous
//
#include <hip/hip_runtime.h>

typedef unsigned short ushort_t;
typedef __attribute__((ext_vector_type(8))) short short8;
typedef __attribute__((ext_vector_type(4))) float floatx4;

#define GAS __attribute__((address_space(1)))
#define LAS __attribute__((address_space(3)))

// ---------- bf16 helpers ----------
__device__ __forceinline__ float bf2f(ushort_t h) {
  union { unsigned int u; float f; } v; v.u = ((unsigned int)h) << 16; return v.f;
}
__device__ __forceinline__ ushort_t f2bf(float f) {  // round-to-nearest-even
  union { float f; unsigned int u; } v; v.f = f;
  unsigned int u = v.u;
  unsigned int r = (u + 0x7fffu + ((u >> 16) & 1u)) >> 16;
  return (ushort_t)r;
}
__device__ __forceinline__ float blo(unsigned int u) { union { unsigned int u; float f; } v; v.u = u << 16; return v.f; }
__device__ __forceinline__ float bhi(unsigned int u) { union { unsigned int u; float f; } v; v.u = u & 0xffff0000u; return v.f; }

// ---------- problem constants ----------
#define T_TOK 4096
#define DIM   1024
#define FDIM  4096
#define NEXP  8
#define MAXROWS 9216   // 8192 pairs + per-expert pad to 128

// ================= input dtype probe: 0 = bf16, 1 = fp32 =================
__global__ void detect_kernel(const ushort_t* __restrict__ xraw, int* __restrict__ dflag) {
  __shared__ int cnt;
  if (threadIdx.x == 0) cnt = 0;
  __syncthreads();
  int c = 0;
#pragma unroll
  for (int i = 0; i < 4; ++i) {
    ushort_t u = xraw[(threadIdx.x * 4 + i) * 2];   // even indices (fp32 low-mantissa halves)
    int e = (u >> 7) & 0xFF;
    if (e >= 100 && e <= 140) c++;
  }
  atomicAdd(&cnt, c);
  __syncthreads();
  if (threadIdx.x == 0) dflag[0] = (cnt > 600) ? 0 : 1;
}

// ================= cast/copy x -> bf16 xb =================
__global__ void __launch_bounds__(256) castx_kernel(const void* __restrict__ xraw,
                                                    const int* __restrict__ dflag,
                                                    ushort_t* __restrict__ xb) {
  const int t = blockIdx.x * 256 + threadIdx.x;     // 8 elements per thread
  const size_t base = (size_t)t * 8;
  if (dflag[0]) {
    const float4* f = (const float4*)((const float*)xraw + base);
    float4 a = f[0], b = f[1];
    ushort_t o[8] = { f2bf(a.x), f2bf(a.y), f2bf(a.z), f2bf(a.w),
                      f2bf(b.x), f2bf(b.y), f2bf(b.z), f2bf(b.w) };
    *(uint4*)(xb + base) = *(const uint4*)o;
  } else {
    *(uint4*)(xb + base) = *((const uint4*)xraw + t);
  }
}

// ================= router: 1 wave per token, fp64 logit accumulation =================
// Routing is a DISCRETE decision (top-2 selection): logits must be computed at
// full precision from the raw fp32 inputs or rare near-ties flip vs reference.
__global__ void __launch_bounds__(256) router_kernel(
    const void* __restrict__ x_, const ushort_t* __restrict__ xb,
    const void* __restrict__ rw_, const void* __restrict__ rb_,
    const int* __restrict__ dflag,
    int* __restrict__ topk_idx, float* __restrict__ topk_wgt, int* __restrict__ counts) {
  const int lane = threadIdx.x & 63;
  const int w = threadIdx.x >> 6;
  const int t = blockIdx.x * 4 + w;
  const int isf32 = dflag[0];
  double logits[NEXP];
  if (isf32) {
    const float* xr = (const float*)x_ + (size_t)t * DIM;
    float xv[16];
#pragma unroll
    for (int i = 0; i < 8; ++i) {
      const float2 v = *(const float2*)(xr + i * 128 + lane * 2);
      xv[2*i] = v.x; xv[2*i+1] = v.y;
    }
#pragma unroll
    for (int e = 0; e < NEXP; ++e) {
      const float* wr = (const float*)rw_ + (size_t)e * DIM;
      double acc = 0.0;
#pragma unroll
      for (int i = 0; i < 8; ++i) {
        const float2 v = *(const float2*)(wr + i * 128 + lane * 2);
        acc += (double)xv[2*i] * (double)v.x + (double)xv[2*i+1] * (double)v.y;
      }
#pragma unroll
      for (int off = 32; off > 0; off >>= 1) acc += __shfl_xor(acc, off, 64);
      logits[e] = acc + (double)((const float*)rb_)[e];
    }
  } else {
    const ushort_t* xr = xb + (size_t)t * DIM;
    float xv[16];
#pragma unroll
    for (int i = 0; i < 8; ++i) {
      unsigned int u = *(const unsigned int*)(xr + i * 128 + lane * 2);
      xv[2*i] = blo(u); xv[2*i+1] = bhi(u);
    }
#pragma unroll
    for (int e = 0; e < NEXP; ++e) {
      const ushort_t* wr = (const ushort_t*)rw_ + (size_t)e * DIM;
      float acc = 0.f;
#pragma unroll
      for (int i = 0; i < 8; ++i) {
        unsigned int u = *(const unsigned int*)(wr + i * 128 + lane * 2);
        acc += xv[2*i] * blo(u) + xv[2*i+1] * bhi(u);
      }
#pragma unroll
      for (int off = 32; off > 0; off >>= 1) acc += __shfl_xor(acc, off, 64);
      logits[e] = (double)(acc + bf2f(((const ushort_t*)rb_)[e]));
    }
  }
  if (lane == 0) {
    double l1 = -1e300, l2 = -1e300; int i1 = 0, i2 = 0;
#pragma unroll
    for (int e = 0; e < NEXP; ++e) {
      double l = logits[e];
      if (l > l1) { l2 = l1; i2 = i1; l1 = l; i1 = e; }
      else if (l > l2) { l2 = l; i2 = e; }
    }
    float wa = (float)(1.0 / (1.0 + exp(l2 - l1)));   // softmax->top2->renorm
    topk_idx[2*t] = i1; topk_idx[2*t+1] = i2;
    topk_wgt[2*t] = wa; topk_wgt[2*t+1] = 1.f - wa;
    atomicAdd(&counts[i1], 1);
    atomicAdd(&counts[i2], 1);
  }
}

// ================= tiny scan: padded exclusive offsets =================
__global__ void scan_kernel(const int* __restrict__ counts, int* __restrict__ offsets) {
  if (threadIdx.x == 0 && blockIdx.x == 0) {
    int s = 0; offsets[0] = 0;
    for (int e = 0; e < NEXP; ++e) { s += (counts[e] + 127) & ~127; offsets[e + 1] = s; }
  }
}

// ================= scatter pairs into per-expert row lists =================
__global__ void __launch_bounds__(256) scatter_kernel(
    const int* __restrict__ topk_idx, const float* __restrict__ topk_wgt,
    const int* __restrict__ offsets, int* __restrict__ cursors,
    int* __restrict__ row_tok, float* __restrict__ row_wgt) {
  int p = blockIdx.x * 256 + threadIdx.x;   // 0..8191
  int e = topk_idx[p];
  int pos = atomicAdd(&cursors[e], 1);
  int r = offsets[e] + pos;
  row_tok[r] = p >> 1;
  row_wgt[r] = topk_wgt[p];
}

// ================= transpose: src [R][C] (fp32 or bf16) -> dst bf16 [C][R] =================
__global__ void __launch_bounds__(256) transpose_kernel(
    const void* __restrict__ src_, ushort_t* __restrict__ dst, int R, int C,
    const int* __restrict__ dflag) {
  __shared__ unsigned int tile[64][33];
  const int e = blockIdx.z;
  const int r0 = blockIdx.y * 64;
  const int c0 = blockIdx.x * 64;
  const int tx = threadIdx.x;
  if (dflag[0]) {
    const float* S = (const float*)src_ + (size_t)e * R * C;
#pragma unroll
    for (int it = 0; it < 8; ++it) {
      int slot = tx + it * 256;       // 2048 slots: 64 rows x 32 uint-cols
      int r = slot >> 5;
      int c2 = slot & 31;
      const float2 v = *(const float2*)(S + (size_t)(r0 + r) * C + c0 + c2 * 2);
      tile[r][c2] = (unsigned int)f2bf(v.x) | ((unsigned int)f2bf(v.y) << 16);
    }
  } else {
    const ushort_t* S = (const ushort_t*)src_ + (size_t)e * R * C;
#pragma unroll
    for (int it = 0; it < 2; ++it) {
      int slot = tx + it * 256;       // 512 slots: 64 rows x 8 chunks
      int r = slot >> 3;
      int cc = slot & 7;
      const uint4 v = *(const uint4*)(S + (size_t)(r0 + r) * C + c0 + cc * 8);
      tile[r][cc*4+0] = v.x; tile[r][cc*4+1] = v.y; tile[r][cc*4+2] = v.z; tile[r][cc*4+3] = v.w;
    }
  }
  __syncthreads();
#pragma unroll
  for (int it = 0; it < 2; ++it) {
    int slot = tx + it * 256;
    int c = slot >> 3;
    int rr = (slot & 7) * 8;
    unsigned int o[4];
#pragma unroll
    for (int q = 0; q < 4; ++q) {
      unsigned int a = tile[rr + 2*q][c >> 1];
      unsigned int b = tile[rr + 2*q + 1][c >> 1];
      unsigned int ha = (c & 1) ? (a >> 16) : (a & 0xffffu);
      unsigned int hb = (c & 1) ? (b >> 16) : (b & 0xffffu);
      o[q] = ha | (hb << 16);
    }
    *(uint4*)(dst + (size_t)e * R * C + (size_t)(c0 + c) * R + r0 + rr) = *(const uint4*)o;
  }
}

// ================= GEMM helpers (m97 frag layout + bank swizzle) =================
__device__ __forceinline__ int swz(int r) { return (r >> 1) & 3; }

__device__ __forceinline__ void stage_tile(const ushort_t* gbase, int gstride,
                                           int row0, int k0, short* lds_tile,
                                           int wid, int lane) {
#pragma unroll
  for (int tloop = 0; tloop < 2; ++tloop) {
    int tr0 = wid * 32 + tloop * 16;
    int r = tr0 + (lane >> 2);
    int g = (lane & 3) ^ swz(r);
    const ushort_t* gp = gbase + (size_t)(row0 + r) * gstride + k0 + g * 8;
    __builtin_amdgcn_global_load_lds((const GAS void*)gp,
                                     (LAS void*)(lds_tile + tr0 * 32), 16, 0, 0);
  }
}

__device__ __forceinline__ short8 frag_ld(const short* tile, int row, int q) {
  return *(const short8*)(tile + row * 32 + ((q ^ swz(row)) << 3));
}

// expert id for a 128-aligned packed row chunk (experts are 128-padded)
__device__ __forceinline__ int chunk_expert(const int* offsets, int r0) {
  int e = 0;
  while (offsets[e + 1] <= r0) ++e;
  return e;
}

// ================= GEMM1: H = silu(X@W1t^T) * (X@W3t^T) =================
// Flattened grid over packed rows; token-gather fused into the A-stage
// (global_load_lds source address is per-lane, so the indirection is free and
// the token base is K-loop-invariant per lane). T3-minimum 2-phase schedule:
// double-buffered LDS, stage(t+1) issued BEFORE compute(t), ONE barrier/step.
__global__ void __launch_bounds__(256) gemm1_kernel(
    const ushort_t* __restrict__ xb, const ushort_t* __restrict__ w1t, const ushort_t* __restrict__ w3t,
    const int* __restrict__ offsets, const int* __restrict__ row_tok, ushort_t* __restrict__ H) {
  const int r0 = blockIdx.y * 128;
  if (r0 >= offsets[NEXP]) return;
  const int e = chunk_expert(offsets, r0);
  const int fbase = blockIdx.x * 128;
  const ushort_t* w1e = w1t + (size_t)e * FDIM * DIM;
  const ushort_t* w3e = w3t + (size_t)e * FDIM * DIM;

  __shared__ __align__(16) short As[2][4096];
  __shared__ __align__(16) short B1s[2][4096];
  __shared__ __align__(16) short B3s[2][4096];

  const int lane = threadIdx.x & 63;
  const int wid = threadIdx.x >> 6;
  const int wrow = (wid >> 1) * 64;
  const int wcol = (wid & 1) * 64;
  const int l15 = lane & 15;
  const int quad = lane >> 4;

  // per-lane staged-A row and its token base (K-loop-invariant)
  const ushort_t* abase[2];
#pragma unroll
  for (int tl = 0; tl < 2; ++tl) {
    int r = wid * 32 + tl * 16 + (lane >> 2);
    abase[tl] = xb + (size_t)row_tok[r0 + r] * DIM + ((lane & 3) ^ swz(r)) * 8;
  }

  floatx4 acc1[4][4], acc3[4][4];
  const floatx4 z4 = {0.f, 0.f, 0.f, 0.f};
#pragma unroll
  for (int i = 0; i < 4; ++i)
#pragma unroll
    for (int j = 0; j < 4; ++j) { acc1[i][j] = z4; acc3[i][j] = z4; }

  auto stageA = [&](int k0, int buf) {
#pragma unroll
    for (int tl = 0; tl < 2; ++tl) {
      int tr0 = wid * 32 + tl * 16;
      __builtin_amdgcn_global_load_lds((const GAS void*)(abase[tl] + k0),
                                       (LAS void*)(&As[buf][tr0 * 32]), 16, 0, 0);
    }
  };
  auto compute = [&](int buf) {
    short8 a[4], b1[4], b3[4];
#pragma unroll
    for (int i = 0; i < 4; ++i) a[i] = frag_ld(&As[buf][0], wrow + i * 16 + l15, quad);
#pragma unroll
    for (int j = 0; j < 4; ++j) {
      b1[j] = frag_ld(&B1s[buf][0], wcol + j * 16 + l15, quad);
      b3[j] = frag_ld(&B3s[buf][0], wcol + j * 16 + l15, quad);
    }
#pragma unroll
    for (int i = 0; i < 4; ++i)
#pragma unroll
      for (int j = 0; j < 4; ++j) {
        acc1[i][j] = __builtin_amdgcn_mfma_f32_16x16x32_bf16(a[i], b1[j], acc1[i][j], 0, 0, 0);
        acc3[i][j] = __builtin_amdgcn_mfma_f32_16x16x32_bf16(a[i], b3[j], acc3[i][j], 0, 0, 0);
      }
  };

  // prologue
  stageA(0, 0);
  stage_tile(w1e, DIM, fbase, 0, &B1s[0][0], wid, lane);
  stage_tile(w3e, DIM, fbase, 0, &B3s[0][0], wid, lane);
  __syncthreads();
  int cur = 0;
  for (int t = 0; t < DIM / 32 - 1; ++t) {
    const int k0n = (t + 1) * 32;
    stageA(k0n, cur ^ 1);
    stage_tile(w1e, DIM, fbase, k0n, &B1s[cur ^ 1][0], wid, lane);
    stage_tile(w3e, DIM, fbase, k0n, &B3s[cur ^ 1][0], wid, lane);
    compute(cur);
    __syncthreads();   // drains vmcnt(0): buf cur^1 ready; buf cur free
    cur ^= 1;
  }
  compute(cur);

#pragma unroll
  for (int i = 0; i < 4; ++i)
#pragma unroll
    for (int j = 0; j < 4; ++j) {
      const int n = fbase + wcol + j * 16 + l15;
#pragma unroll
      for (int p = 0; p < 4; ++p) {
        const int rl = wrow + i * 16 + quad * 4 + p;
        float zt = acc1[i][j][p];
        float vt = acc3[i][j][p];
        float s = zt / (1.f + __expf(-zt));   // silu
        H[(size_t)(r0 + rl) * FDIM + n] = f2bf(s * vt);
      }
    }
}

// ================= GEMM2: out[tok] += wgt * (H @ W2t^T)  (fp32 output) =================
__global__ void __launch_bounds__(256) gemm2_kernel(
    const ushort_t* __restrict__ H, const ushort_t* __restrict__ w2t,
    const int* __restrict__ offsets, const int* __restrict__ row_tok,
    const float* __restrict__ row_wgt, float* __restrict__ out) {
  const int r0 = blockIdx.y * 128;
  if (r0 >= offsets[NEXP]) return;
  const int e = chunk_expert(offsets, r0);
  const int dbase = blockIdx.x * 128;
  const ushort_t* w2e = w2t + (size_t)e * DIM * FDIM;

  __shared__ __align__(16) short As[2][4096];
  __shared__ __align__(16) short Bs[2][4096];

  const int lane = threadIdx.x & 63;
  const int wid = threadIdx.x >> 6;
  const int wrow = (wid >> 1) * 64;
  const int wcol = (wid & 1) * 64;
  const int l15 = lane & 15;
  const int quad = lane >> 4;

  floatx4 acc[4][4];
  const floatx4 z4 = {0.f, 0.f, 0.f, 0.f};
#pragma unroll
  for (int i = 0; i < 4; ++i)
#pragma unroll
    for (int j = 0; j < 4; ++j) acc[i][j] = z4;

  auto compute = [&](int buf) {
    short8 a[4], b[4];
#pragma unroll
    for (int i = 0; i < 4; ++i) a[i] = frag_ld(&As[buf][0], wrow + i * 16 + l15, quad);
#pragma unroll
    for (int j = 0; j < 4; ++j) b[j] = frag_ld(&Bs[buf][0], wcol + j * 16 + l15, quad);
#pragma unroll
    for (int i = 0; i < 4; ++i)
#pragma unroll
      for (int j = 0; j < 4; ++j)
        acc[i][j] = __builtin_amdgcn_mfma_f32_16x16x32_bf16(a[i], b[j], acc[i][j], 0, 0, 0);
  };

  // prologue
  stage_tile(H,   FDIM, r0,    0, &As[0][0], wid, lane);
  stage_tile(w2e, FDIM, dbase, 0, &Bs[0][0], wid, lane);
  __syncthreads();
  int cur = 0;
  for (int t = 0; t < FDIM / 32 - 1; ++t) {
    const int k0n = (t + 1) * 32;
    stage_tile(H,   FDIM, r0,    k0n, &As[cur ^ 1][0], wid, lane);
    stage_tile(w2e, FDIM, dbase, k0n, &Bs[cur ^ 1][0], wid, lane);
    compute(cur);
    __syncthreads();
    cur ^= 1;
  }
  compute(cur);

#pragma unroll
  for (int i = 0; i < 4; ++i) {
    int tok[4]; float wgt[4];
#pragma unroll
    for (int p = 0; p < 4; ++p) {
      int rl = r0 + wrow + i * 16 + quad * 4 + p;
      tok[p] = row_tok[rl];
      wgt[p] = row_wgt[rl];   // 0.0 on padding rows
    }
#pragma unroll
    for (int j = 0; j < 4; ++j) {
      int n = dbase + wcol + j * 16 + l15;
#pragma unroll
      for (int p = 0; p < 4; ++p)
        if (wgt[p] != 0.f)
          atomicAdd(&out[(size_t)tok[p] * DIM + n], wgt[p] * acc[i][j][p]);
    }
  }
}

// ================= host launch =================
extern "C" void kernel_launch(void* const* d_in, const int* in_sizes, int n_in,
                              void* d_out, int out_size, void* d_ws, size_t ws_size,
                              hipStream_t stream) {
  const void* x  = d_in[0];
  const void* rw = d_in[1];
  const void* rb = d_in[2];
  const void* w1 = d_in[3];
  const void* w2 = d_in[4];
  const void* w3 = d_in[5];
  float* out = (float*)d_out;   // fp32 output

  char* ws = (char*)d_ws;
  size_t off = 0;
  auto alloc = [&](size_t bytes) { size_t o = off; off += (bytes + 255) & ~(size_t)255; return o; };
  int*      dflag    = (int*)(ws + alloc(64));
  int*      counts   = (int*)(ws + alloc(64));
  int*      cursors  = (int*)(ws + alloc(64));
  int*      offsets  = (int*)(ws + alloc(64));
  int*      topk_idx = (int*)(ws + alloc((size_t)T_TOK * 2 * 4));
  float*    topk_wgt = (float*)(ws + alloc((size_t)T_TOK * 2 * 4));
  int*      row_tok  = (int*)(ws + alloc((size_t)MAXROWS * 4));
  float*    row_wgt  = (float*)(ws + alloc((size_t)MAXROWS * 4));
  ushort_t* xb       = (ushort_t*)(ws + alloc((size_t)T_TOK * DIM * 2));
  ushort_t* Hbuf     = (ushort_t*)(ws + alloc((size_t)MAXROWS * FDIM * 2));
  ushort_t* w1t      = (ushort_t*)(ws + alloc((size_t)NEXP * FDIM * DIM * 2));
  ushort_t* w3t      = (ushort_t*)(ws + alloc((size_t)NEXP * FDIM * DIM * 2));
  ushort_t* w2t      = (ushort_t*)(ws + alloc((size_t)NEXP * DIM * FDIM * 2));

  hipMemsetAsync(counts, 0, 64, stream);
  hipMemsetAsync(cursors, 0, 64, stream);
  hipMemsetAsync(row_tok, 0, (size_t)MAXROWS * 4, stream);
  hipMemsetAsync(row_wgt, 0, (size_t)MAXROWS * 4, stream);
  // Zero exactly the harness-provided output buffer (harness poisons with 0xAA;
  // gemm2 accumulates with atomicAdd so it must start at 0).
  hipMemsetAsync(out, 0, (size_t)out_size, stream);

  detect_kernel<<<1, 256, 0, stream>>>((const ushort_t*)x, dflag);
  castx_kernel<<<(T_TOK * DIM / 8) / 256, 256, 0, stream>>>(x, dflag, xb);
  router_kernel<<<T_TOK / 4, 256, 0, stream>>>(x, xb, rw, rb, dflag, topk_idx, topk_wgt, counts);
  scan_kernel<<<1, 64, 0, stream>>>(counts, offsets);
  scatter_kernel<<<(T_TOK * 2) / 256, 256, 0, stream>>>(topk_idx, topk_wgt, offsets, cursors, row_tok, row_wgt);
  // w1,w3: [D][F] -> [F][D];  w2: [F][D] -> [D][F]
  transpose_kernel<<<dim3(FDIM / 64, DIM / 64, NEXP), 256, 0, stream>>>(w1, w1t, DIM, FDIM, dflag);
  transpose_kernel<<<dim3(FDIM / 64, DIM / 64, NEXP), 256, 0, stream>>>(w3, w3t, DIM, FDIM, dflag);
  transpose_kernel<<<dim3(DIM / 64, FDIM / 64, NEXP), 256, 0, stream>>>(w2, w2t, FDIM, DIM, dflag);
  // flattened grids over the packed row space (no per-expert z-dim, no empty dispatch storm)
  gemm1_kernel<<<dim3(FDIM / 128, MAXROWS / 128), 256, 0, stream>>>(xb, w1t, w3t, offsets, row_tok, Hbuf);
  gemm2_kernel<<<dim3(DIM / 128, MAXROWS / 128), 256, 0, stream>>>(Hbuf, w2t, offsets, row_tok, row_wgt, out);
}

// Round 3
// 968.358 us; speedup vs baseline: 1.1253x; 1.0213x over previous
//
#include <hip/hip_runtime.h>

typedef unsigned short ushort_t;
typedef __attribute__((ext_vector_type(8))) short short8;
typedef __attribute__((ext_vector_type(4))) float floatx4;

#define GAS __attribute__((address_space(1)))
#define LAS __attribute__((address_space(3)))

// ---------- bf16 helpers ----------
__device__ __forceinline__ float bf2f(ushort_t h) {
  union { unsigned int u; float f; } v; v.u = ((unsigned int)h) << 16; return v.f;
}
__device__ __forceinline__ ushort_t f2bf(float f) {  // round-to-nearest-even
  union { float f; unsigned int u; } v; v.f = f;
  unsigned int u = v.u;
  unsigned int r = (u + 0x7fffu + ((u >> 16) & 1u)) >> 16;
  return (ushort_t)r;
}
__device__ __forceinline__ float blo(unsigned int u) { union { unsigned int u; float f; } v; v.u = u << 16; return v.f; }
__device__ __forceinline__ float bhi(unsigned int u) { union { unsigned int u; float f; } v; v.u = u & 0xffff0000u; return v.f; }

// ---------- problem constants ----------
#define T_TOK 4096
#define DIM   1024
#define FDIM  4096
#define NEXP  8
#define MAXROWS 9216   // 8192 pairs + per-expert pad to 128

// ================= input dtype probe: 0 = bf16, 1 = fp32 =================
__global__ void detect_kernel(const ushort_t* __restrict__ xraw, int* __restrict__ dflag) {
  __shared__ int cnt;
  if (threadIdx.x == 0) cnt = 0;
  __syncthreads();
  int c = 0;
#pragma unroll
  for (int i = 0; i < 4; ++i) {
    ushort_t u = xraw[(threadIdx.x * 4 + i) * 2];   // even indices (fp32 low-mantissa halves)
    int e = (u >> 7) & 0xFF;
    if (e >= 100 && e <= 140) c++;
  }
  atomicAdd(&cnt, c);
  __syncthreads();
  if (threadIdx.x == 0) dflag[0] = (cnt > 600) ? 0 : 1;
}

// ================= cast/copy x -> bf16 xb =================
__global__ void __launch_bounds__(256) castx_kernel(const void* __restrict__ xraw,
                                                    const int* __restrict__ dflag,
                                                    ushort_t* __restrict__ xb) {
  const int t = blockIdx.x * 256 + threadIdx.x;     // 8 elements per thread
  const size_t base = (size_t)t * 8;
  if (dflag[0]) {
    const float4* f = (const float4*)((const float*)xraw + base);
    float4 a = f[0], b = f[1];
    ushort_t o[8] = { f2bf(a.x), f2bf(a.y), f2bf(a.z), f2bf(a.w),
                      f2bf(b.x), f2bf(b.y), f2bf(b.z), f2bf(b.w) };
    *(uint4*)(xb + base) = *(const uint4*)o;
  } else {
    *(uint4*)(xb + base) = *((const uint4*)xraw + t);
  }
}

// ================= router: 1 wave per token, fp64 logit accumulation =================
// Routing is a DISCRETE decision (top-2 selection): logits must be computed at
// full precision from the raw fp32 inputs or rare near-ties flip vs reference.
__global__ void __launch_bounds__(256) router_kernel(
    const void* __restrict__ x_, const ushort_t* __restrict__ xb,
    const void* __restrict__ rw_, const void* __restrict__ rb_,
    const int* __restrict__ dflag,
    int* __restrict__ topk_idx, float* __restrict__ topk_wgt, int* __restrict__ counts) {
  const int lane = threadIdx.x & 63;
  const int w = threadIdx.x >> 6;
  const int t = blockIdx.x * 4 + w;
  const int isf32 = dflag[0];
  double logits[NEXP];
  if (isf32) {
    const float* xr = (const float*)x_ + (size_t)t * DIM;
    float xv[16];
#pragma unroll
    for (int i = 0; i < 8; ++i) {
      const float2 v = *(const float2*)(xr + i * 128 + lane * 2);
      xv[2*i] = v.x; xv[2*i+1] = v.y;
    }
#pragma unroll
    for (int e = 0; e < NEXP; ++e) {
      const float* wr = (const float*)rw_ + (size_t)e * DIM;
      double acc = 0.0;
#pragma unroll
      for (int i = 0; i < 8; ++i) {
        const float2 v = *(const float2*)(wr + i * 128 + lane * 2);
        acc += (double)xv[2*i] * (double)v.x + (double)xv[2*i+1] * (double)v.y;
      }
#pragma unroll
      for (int off = 32; off > 0; off >>= 1) acc += __shfl_xor(acc, off, 64);
      logits[e] = acc + (double)((const float*)rb_)[e];
    }
  } else {
    const ushort_t* xr = xb + (size_t)t * DIM;
    float xv[16];
#pragma unroll
    for (int i = 0; i < 8; ++i) {
      unsigned int u = *(const unsigned int*)(xr + i * 128 + lane * 2);
      xv[2*i] = blo(u); xv[2*i+1] = bhi(u);
    }
#pragma unroll
    for (int e = 0; e < NEXP; ++e) {
      const ushort_t* wr = (const ushort_t*)rw_ + (size_t)e * DIM;
      float acc = 0.f;
#pragma unroll
      for (int i = 0; i < 8; ++i) {
        unsigned int u = *(const unsigned int*)(wr + i * 128 + lane * 2);
        acc += xv[2*i] * blo(u) + xv[2*i+1] * bhi(u);
      }
#pragma unroll
      for (int off = 32; off > 0; off >>= 1) acc += __shfl_xor(acc, off, 64);
      logits[e] = (double)(acc + bf2f(((const ushort_t*)rb_)[e]));
    }
  }
  if (lane == 0) {
    double l1 = -1e300, l2 = -1e300; int i1 = 0, i2 = 0;
#pragma unroll
    for (int e = 0; e < NEXP; ++e) {
      double l = logits[e];
      if (l > l1) { l2 = l1; i2 = i1; l1 = l; i1 = e; }
      else if (l > l2) { l2 = l; i2 = e; }
    }
    float wa = (float)(1.0 / (1.0 + exp(l2 - l1)));   // softmax->top2->renorm
    topk_idx[2*t] = i1; topk_idx[2*t+1] = i2;
    topk_wgt[2*t] = wa; topk_wgt[2*t+1] = 1.f - wa;
    atomicAdd(&counts[i1], 1);
    atomicAdd(&counts[i2], 1);
  }
}

// ================= tiny scan: padded exclusive offsets =================
__global__ void scan_kernel(const int* __restrict__ counts, int* __restrict__ offsets) {
  if (threadIdx.x == 0 && blockIdx.x == 0) {
    int s = 0; offsets[0] = 0;
    for (int e = 0; e < NEXP; ++e) { s += (counts[e] + 127) & ~127; offsets[e + 1] = s; }
  }
}

// ================= scatter pairs into per-expert row lists =================
__global__ void __launch_bounds__(256) scatter_kernel(
    const int* __restrict__ topk_idx, const float* __restrict__ topk_wgt,
    const int* __restrict__ offsets, int* __restrict__ cursors,
    int* __restrict__ row_tok, float* __restrict__ row_wgt) {
  int p = blockIdx.x * 256 + threadIdx.x;   // 0..8191
  int e = topk_idx[p];
  int pos = atomicAdd(&cursors[e], 1);
  int r = offsets[e] + pos;
  row_tok[r] = p >> 1;
  row_wgt[r] = topk_wgt[p];
}

// ================= transpose: src [R][C] (fp32 or bf16) -> dst bf16 [C][R] =================
__global__ void __launch_bounds__(256) transpose_kernel(
    const void* __restrict__ src_, ushort_t* __restrict__ dst, int R, int C,
    const int* __restrict__ dflag) {
  __shared__ unsigned int tile[64][33];
  const int e = blockIdx.z;
  const int r0 = blockIdx.y * 64;
  const int c0 = blockIdx.x * 64;
  const int tx = threadIdx.x;
  if (dflag[0]) {
    const float* S = (const float*)src_ + (size_t)e * R * C;
#pragma unroll
    for (int it = 0; it < 8; ++it) {
      int slot = tx + it * 256;       // 2048 slots: 64 rows x 32 uint-cols
      int r = slot >> 5;
      int c2 = slot & 31;
      const float2 v = *(const float2*)(S + (size_t)(r0 + r) * C + c0 + c2 * 2);
      tile[r][c2] = (unsigned int)f2bf(v.x) | ((unsigned int)f2bf(v.y) << 16);
    }
  } else {
    const ushort_t* S = (const ushort_t*)src_ + (size_t)e * R * C;
#pragma unroll
    for (int it = 0; it < 2; ++it) {
      int slot = tx + it * 256;       // 512 slots: 64 rows x 8 chunks
      int r = slot >> 3;
      int cc = slot & 7;
      const uint4 v = *(const uint4*)(S + (size_t)(r0 + r) * C + c0 + cc * 8);
      tile[r][cc*4+0] = v.x; tile[r][cc*4+1] = v.y; tile[r][cc*4+2] = v.z; tile[r][cc*4+3] = v.w;
    }
  }
  __syncthreads();
#pragma unroll
  for (int it = 0; it < 2; ++it) {
    int slot = tx + it * 256;
    int c = slot >> 3;
    int rr = (slot & 7) * 8;
    unsigned int o[4];
#pragma unroll
    for (int q = 0; q < 4; ++q) {
      unsigned int a = tile[rr + 2*q][c >> 1];
      unsigned int b = tile[rr + 2*q + 1][c >> 1];
      unsigned int ha = (c & 1) ? (a >> 16) : (a & 0xffffu);
      unsigned int hb = (c & 1) ? (b >> 16) : (b & 0xffffu);
      o[q] = ha | (hb << 16);
    }
    *(uint4*)(dst + (size_t)e * R * C + (size_t)(c0 + c) * R + r0 + rr) = *(const uint4*)o;
  }
}

// ================= GEMM helpers (m97 frag layout + bank swizzle) =================
__device__ __forceinline__ int swz(int r) { return (r >> 1) & 3; }

__device__ __forceinline__ short8 frag_ld(const short* tile, int row, int q) {
  return *(const short8*)(tile + row * 32 + ((q ^ swz(row)) << 3));
}

// expert id for a 128-aligned packed row chunk (experts are 128-padded)
__device__ __forceinline__ int chunk_expert(const int* offsets, int r0) {
  int e = 0;
  while (offsets[e + 1] <= r0) ++e;
  return e;
}

// ================= GEMM1: H = silu(X@W1t^T) * (X@W3t^T) =================
// Flattened grid over packed rows; token-gather fused into the A-stage.
// 2-phase dbuf schedule (stage(t+1) before compute(t), one barrier/step).
// ALL staging addresses hoisted to K-loop-invariant per-lane pointers:
// round-2 counters showed VALUBusy 43% vs MfmaUtil 19.6% — per-step 64-bit
// address recompute (mul chains) dominated the critical path at ~2 blocks/CU.
__global__ void __launch_bounds__(256) gemm1_kernel(
    const ushort_t* __restrict__ xb, const ushort_t* __restrict__ w1t, const ushort_t* __restrict__ w3t,
    const int* __restrict__ offsets, const int* __restrict__ row_tok, ushort_t* __restrict__ H) {
  const int r0 = blockIdx.y * 128;
  if (r0 >= offsets[NEXP]) return;
  const int e = chunk_expert(offsets, r0);
  const int fbase = blockIdx.x * 128;
  const ushort_t* w1e = w1t + (size_t)e * FDIM * DIM;
  const ushort_t* w3e = w3t + (size_t)e * FDIM * DIM;

  __shared__ __align__(16) short As[2][4096];
  __shared__ __align__(16) short B1s[2][4096];
  __shared__ __align__(16) short B3s[2][4096];

  const int lane = threadIdx.x & 63;
  const int wid = threadIdx.x >> 6;
  const int wrow = (wid >> 1) * 64;
  const int wcol = (wid & 1) * 64;
  const int l15 = lane & 15;
  const int quad = lane >> 4;

  // K-loop-invariant per-lane staging pointers (one address calc total)
  const ushort_t* aP[2];  const ushort_t* b1P[2];  const ushort_t* b3P[2];
  int ldst[2];   // LDS short-offset of this lane's wave-uniform dst slice base
#pragma unroll
  for (int tl = 0; tl < 2; ++tl) {
    const int tr0 = wid * 32 + tl * 16;
    const int r = tr0 + (lane >> 2);
    const int g = ((lane & 3) ^ swz(r)) * 8;
    aP[tl]  = xb  + (size_t)row_tok[r0 + r] * DIM + g;
    b1P[tl] = w1e + (size_t)(fbase + r) * DIM + g;
    b3P[tl] = w3e + (size_t)(fbase + r) * DIM + g;
    ldst[tl] = tr0 * 32;
  }

  floatx4 acc1[4][4], acc3[4][4];
  const floatx4 z4 = {0.f, 0.f, 0.f, 0.f};
#pragma unroll
  for (int i = 0; i < 4; ++i)
#pragma unroll
    for (int j = 0; j < 4; ++j) { acc1[i][j] = z4; acc3[i][j] = z4; }

  auto stage = [&](int k0, int buf) {
#pragma unroll
    for (int tl = 0; tl < 2; ++tl) {
      __builtin_amdgcn_global_load_lds((const GAS void*)(aP[tl]  + k0), (LAS void*)(&As[buf][ldst[tl]]),  16, 0, 0);
      __builtin_amdgcn_global_load_lds((const GAS void*)(b1P[tl] + k0), (LAS void*)(&B1s[buf][ldst[tl]]), 16, 0, 0);
      __builtin_amdgcn_global_load_lds((const GAS void*)(b3P[tl] + k0), (LAS void*)(&B3s[buf][ldst[tl]]), 16, 0, 0);
    }
  };
  auto compute = [&](int buf) {
    short8 a[4], b1[4], b3[4];
#pragma unroll
    for (int i = 0; i < 4; ++i) a[i] = frag_ld(&As[buf][0], wrow + i * 16 + l15, quad);
#pragma unroll
    for (int j = 0; j < 4; ++j) {
      b1[j] = frag_ld(&B1s[buf][0], wcol + j * 16 + l15, quad);
      b3[j] = frag_ld(&B3s[buf][0], wcol + j * 16 + l15, quad);
    }
#pragma unroll
    for (int i = 0; i < 4; ++i)
#pragma unroll
      for (int j = 0; j < 4; ++j) {
        acc1[i][j] = __builtin_amdgcn_mfma_f32_16x16x32_bf16(a[i], b1[j], acc1[i][j], 0, 0, 0);
        acc3[i][j] = __builtin_amdgcn_mfma_f32_16x16x32_bf16(a[i], b3[j], acc3[i][j], 0, 0, 0);
      }
  };

  // prologue
  stage(0, 0);
  __syncthreads();
  int cur = 0;
  for (int t = 0; t < DIM / 32 - 1; ++t) {
    stage((t + 1) * 32, cur ^ 1);
    compute(cur);
    __syncthreads();   // drains vmcnt(0): buf cur^1 ready; buf cur free
    cur ^= 1;
  }
  compute(cur);

#pragma unroll
  for (int i = 0; i < 4; ++i)
#pragma unroll
    for (int j = 0; j < 4; ++j) {
      const int n = fbase + wcol + j * 16 + l15;
#pragma unroll
      for (int p = 0; p < 4; ++p) {
        const int rl = wrow + i * 16 + quad * 4 + p;
        float zt = acc1[i][j][p];
        float vt = acc3[i][j][p];
        float s = zt / (1.f + __expf(-zt));   // silu
        H[(size_t)(r0 + rl) * FDIM + n] = f2bf(s * vt);
      }
    }
}

// ================= GEMM2: out[tok] += wgt * (H @ W2t^T)  (fp32 output) =================
__global__ void __launch_bounds__(256) gemm2_kernel(
    const ushort_t* __restrict__ H, const ushort_t* __restrict__ w2t,
    const int* __restrict__ offsets, const int* __restrict__ row_tok,
    const float* __restrict__ row_wgt, float* __restrict__ out) {
  const int r0 = blockIdx.y * 128;
  if (r0 >= offsets[NEXP]) return;
  const int e = chunk_expert(offsets, r0);
  const int dbase = blockIdx.x * 128;
  const ushort_t* w2e = w2t + (size_t)e * DIM * FDIM;

  __shared__ __align__(16) short As[2][4096];
  __shared__ __align__(16) short Bs[2][4096];

  const int lane = threadIdx.x & 63;
  const int wid = threadIdx.x >> 6;
  const int wrow = (wid >> 1) * 64;
  const int wcol = (wid & 1) * 64;
  const int l15 = lane & 15;
  const int quad = lane >> 4;

  // K-loop-invariant per-lane staging pointers
  const ushort_t* aP[2];  const ushort_t* bP[2];
  int ldst[2];
#pragma unroll
  for (int tl = 0; tl < 2; ++tl) {
    const int tr0 = wid * 32 + tl * 16;
    const int r = tr0 + (lane >> 2);
    const int g = ((lane & 3) ^ swz(r)) * 8;
    aP[tl] = H   + (size_t)(r0 + r) * FDIM + g;
    bP[tl] = w2e + (size_t)(dbase + r) * FDIM + g;
    ldst[tl] = tr0 * 32;
  }

  floatx4 acc[4][4];
  const floatx4 z4 = {0.f, 0.f, 0.f, 0.f};
#pragma unroll
  for (int i = 0; i < 4; ++i)
#pragma unroll
    for (int j = 0; j < 4; ++j) acc[i][j] = z4;

  auto stage = [&](int k0, int buf) {
#pragma unroll
    for (int tl = 0; tl < 2; ++tl) {
      __builtin_amdgcn_global_load_lds((const GAS void*)(aP[tl] + k0), (LAS void*)(&As[buf][ldst[tl]]), 16, 0, 0);
      __builtin_amdgcn_global_load_lds((const GAS void*)(bP[tl] + k0), (LAS void*)(&Bs[buf][ldst[tl]]), 16, 0, 0);
    }
  };
  auto compute = [&](int buf) {
    short8 a[4], b[4];
#pragma unroll
    for (int i = 0; i < 4; ++i) a[i] = frag_ld(&As[buf][0], wrow + i * 16 + l15, quad);
#pragma unroll
    for (int j = 0; j < 4; ++j) b[j] = frag_ld(&Bs[buf][0], wcol + j * 16 + l15, quad);
#pragma unroll
    for (int i = 0; i < 4; ++i)
#pragma unroll
      for (int j = 0; j < 4; ++j)
        acc[i][j] = __builtin_amdgcn_mfma_f32_16x16x32_bf16(a[i], b[j], acc[i][j], 0, 0, 0);
  };

  // prologue
  stage(0, 0);
  __syncthreads();
  int cur = 0;
  for (int t = 0; t < FDIM / 32 - 1; ++t) {
    stage((t + 1) * 32, cur ^ 1);
    compute(cur);
    __syncthreads();
    cur ^= 1;
  }
  compute(cur);

#pragma unroll
  for (int i = 0; i < 4; ++i) {
    int tok[4]; float wgt[4];
#pragma unroll
    for (int p = 0; p < 4; ++p) {
      int rl = r0 + wrow + i * 16 + quad * 4 + p;
      tok[p] = row_tok[rl];
      wgt[p] = row_wgt[rl];   // 0.0 on padding rows
    }
#pragma unroll
    for (int j = 0; j < 4; ++j) {
      int n = dbase + wcol + j * 16 + l15;
#pragma unroll
      for (int p = 0; p < 4; ++p)
        if (wgt[p] != 0.f)
          atomicAdd(&out[(size_t)tok[p] * DIM + n], wgt[p] * acc[i][j][p]);
    }
  }
}

// ================= host launch =================
extern "C" void kernel_launch(void* const* d_in, const int* in_sizes, int n_in,
                              void* d_out, int out_size, void* d_ws, size_t ws_size,
                              hipStream_t stream) {
  const void* x  = d_in[0];
  const void* rw = d_in[1];
  const void* rb = d_in[2];
  const void* w1 = d_in[3];
  const void* w2 = d_in[4];
  const void* w3 = d_in[5];
  float* out = (float*)d_out;   // fp32 output

  char* ws = (char*)d_ws;
  size_t off = 0;
  auto alloc = [&](size_t bytes) { size_t o = off; off += (bytes + 255) & ~(size_t)255; return o; };
  int*      dflag    = (int*)(ws + alloc(64));
  int*      counts   = (int*)(ws + alloc(64));
  int*      cursors  = (int*)(ws + alloc(64));
  int*      offsets  = (int*)(ws + alloc(64));
  int*      topk_idx = (int*)(ws + alloc((size_t)T_TOK * 2 * 4));
  float*    topk_wgt = (float*)(ws + alloc((size_t)T_TOK * 2 * 4));
  int*      row_tok  = (int*)(ws + alloc((size_t)MAXROWS * 4));
  float*    row_wgt  = (float*)(ws + alloc((size_t)MAXROWS * 4));
  ushort_t* xb       = (ushort_t*)(ws + alloc((size_t)T_TOK * DIM * 2));
  ushort_t* Hbuf     = (ushort_t*)(ws + alloc((size_t)MAXROWS * FDIM * 2));
  ushort_t* w1t      = (ushort_t*)(ws + alloc((size_t)NEXP * FDIM * DIM * 2));
  ushort_t* w3t      = (ushort_t*)(ws + alloc((size_t)NEXP * FDIM * DIM * 2));
  ushort_t* w2t      = (ushort_t*)(ws + alloc((size_t)NEXP * DIM * FDIM * 2));

  hipMemsetAsync(counts, 0, 64, stream);
  hipMemsetAsync(cursors, 0, 64, stream);
  hipMemsetAsync(row_tok, 0, (size_t)MAXROWS * 4, stream);
  hipMemsetAsync(row_wgt, 0, (size_t)MAXROWS * 4, stream);
  // Zero exactly the harness-provided output buffer (harness poisons with 0xAA;
  // gemm2 accumulates with atomicAdd so it must start at 0).
  hipMemsetAsync(out, 0, (size_t)out_size, stream);

  detect_kernel<<<1, 256, 0, stream>>>((const ushort_t*)x, dflag);
  castx_kernel<<<(T_TOK * DIM / 8) / 256, 256, 0, stream>>>(x, dflag, xb);
  router_kernel<<<T_TOK / 4, 256, 0, stream>>>(x, xb, rw, rb, dflag, topk_idx, topk_wgt, counts);
  scan_kernel<<<1, 64, 0, stream>>>(counts, offsets);
  scatter_kernel<<<(T_TOK * 2) / 256, 256, 0, stream>>>(topk_idx, topk_wgt, offsets, cursors, row_tok, row_wgt);
  // w1,w3: [D][F] -> [F][D];  w2: [F][D] -> [D][F]
  transpose_kernel<<<dim3(FDIM / 64, DIM / 64, NEXP), 256, 0, stream>>>(w1, w1t, DIM, FDIM, dflag);
  transpose_kernel<<<dim3(FDIM / 64, DIM / 64, NEXP), 256, 0, stream>>>(w3, w3t, DIM, FDIM, dflag);
  transpose_kernel<<<dim3(DIM / 64, FDIM / 64, NEXP), 256, 0, stream>>>(w2, w2t, FDIM, DIM, dflag);
  // flattened grids over the packed row space
  gemm1_kernel<<<dim3(FDIM / 128, MAXROWS / 128), 256, 0, stream>>>(xb, w1t, w3t, offsets, row_tok, Hbuf);
  gemm2_kernel<<<dim3(DIM / 128, MAXROWS / 128), 256, 0, stream>>>(Hbuf, w2t, offsets, row_tok, row_wgt, out);
}